// Round 13
// baseline (274.019 us; speedup 1.0000x reference)
//
#include <hip/hip_runtime.h>

#define NU 100000
#define NI 50000
#define NE 819200
#define FIN 128
#define HH 32

#define NCH 200         // edge chunks of 4096
#define NBU 98          // user buckets of 1024 nodes
#define NBI 49          // item buckets of 1024 nodes

#define G_P0I 6250      // NI/8
#define G_P0U 12500     // NU/8
#define G_P128U 1563    // ceil(NU/64)
#define G_P128I 782     // ceil(NI/64)

// ================= radix CSR build =================

__global__ void cnt1_k(const int4* __restrict__ eu4, const int4* __restrict__ ei4,
                       int* __restrict__ cntU, int* __restrict__ cntI) {
    __shared__ unsigned cnt[128];
    int b = blockIdx.x;
    int c, NB;
    const int4* D;
    int* M;
    if (b < NCH) { c = b; D = eu4; M = cntU; NB = NBU; }
    else         { c = b - NCH; D = ei4; M = cntI; NB = NBI; }
    int tid = threadIdx.x;
    if (tid < 128) cnt[tid] = 0u;
    __syncthreads();
    int base = c * 1024;
#pragma unroll
    for (int it = 0; it < 4; ++it) {
        int4 v = D[base + it * 256 + tid];
        atomicAdd(&cnt[v.x >> 10], 1u);
        atomicAdd(&cnt[v.y >> 10], 1u);
        atomicAdd(&cnt[v.z >> 10], 1u);
        atomicAdd(&cnt[v.w >> 10], 1u);
    }
    __syncthreads();
    for (int i = tid; i < NB; i += 256) M[i * NCH + c] = (int)cnt[i];
}

__global__ __launch_bounds__(1024) void scan2_k(int* __restrict__ aU, int nU,
                                                int* __restrict__ aI, int nI) {
    __shared__ int ts[1024];
    int t = threadIdx.x;
    for (int pass = 0; pass < 2; ++pass) {
        int* a = pass ? aI : aU;
        int n  = pass ? nI : nU;
        int nper = (n + 1023) / 1024;
        int beg = t * nper;
        int end = beg + nper; if (end > n) end = n;
        int s = 0;
        for (int i = beg; i < end; ++i) s += a[i];
        ts[t] = s;
        __syncthreads();
        int incl = s;
        for (int off = 1; off < 1024; off <<= 1) {
            int y = (t >= off) ? ts[t - off] : 0;
            __syncthreads();
            incl += y;
            ts[t] = incl;
            __syncthreads();
        }
        int run = incl - s;
        for (int i = beg; i < end; ++i) { int v = a[i]; a[i] = run; run += v; }
        __syncthreads();
    }
}

__global__ void part_k(const int4* __restrict__ eu4, const int4* __restrict__ ei4,
                       const int* __restrict__ cntU, const int* __restrict__ cntI,
                       int2* __restrict__ partU, int2* __restrict__ partI) {
    __shared__ unsigned cur[128];
    int b = blockIdx.x;
    int c, NB;
    const int4 *D, *P;
    const int* M;
    int2* out;
    if (b < NCH) { c = b; D = eu4; P = ei4; M = cntU; out = partU; NB = NBU; }
    else         { c = b - NCH; D = ei4; P = eu4; M = cntI; out = partI; NB = NBI; }
    int tid = threadIdx.x;
    for (int i = tid; i < NB; i += 256) cur[i] = (unsigned)M[i * NCH + c];
    __syncthreads();
    int base = c * 1024;
#pragma unroll
    for (int it = 0; it < 4; ++it) {
        int4 d = D[base + it * 256 + tid];
        int4 p = P[base + it * 256 + tid];
        unsigned s;
        s = atomicAdd(&cur[d.x >> 10], 1u); out[s] = make_int2(d.x, p.x);
        s = atomicAdd(&cur[d.y >> 10], 1u); out[s] = make_int2(d.y, p.y);
        s = atomicAdd(&cur[d.z >> 10], 1u); out[s] = make_int2(d.z, p.z);
        s = atomicAdd(&cur[d.w >> 10], 1u); out[s] = make_int2(d.w, p.w);
    }
}

__global__ __launch_bounds__(1024) void build_k(const int2* __restrict__ partU,
                                                const int2* __restrict__ partI,
                                                const int* __restrict__ cntU,
                                                const int* __restrict__ cntI,
                                                int* __restrict__ rsU, int* __restrict__ rsI,
                                                int* __restrict__ csrU, int* __restrict__ csrI) {
    __shared__ unsigned dcnt[1024];
    __shared__ unsigned sc[1024];
    int b = blockIdx.x;
    const int2* part;
    const int* M;
    int *rs, *csr;
    int bi, N, NB;
    if (b < NBU) { bi = b; part = partU; M = cntU; rs = rsU; csr = csrU; N = NU; NB = NBU; }
    else         { bi = b - NBU; part = partI; M = cntI; rs = rsI; csr = csrI; N = NI; NB = NBI; }
    int lo = bi * 1024;
    int bktbase = M[bi * NCH];
    int bktend = (bi + 1 < NB) ? M[(bi + 1) * NCH] : NE;
    int t = threadIdx.x;
    dcnt[t] = 0u;
    __syncthreads();
    for (int j = bktbase + t; j < bktend; j += 1024) {
        int2 p = part[j];
        atomicAdd(&dcnt[p.x - lo], 1u);
    }
    __syncthreads();
    unsigned cme = dcnt[t];
    sc[t] = cme;
    __syncthreads();
    unsigned incl = cme;
    for (int off = 1; off < 1024; off <<= 1) {
        unsigned y = (t >= off) ? sc[t - off] : 0u;
        __syncthreads();
        incl += y;
        sc[t] = incl;
        __syncthreads();
    }
    unsigned excl = incl - cme;
    if (lo + t < N) rs[lo + t] = bktbase + (int)excl;
    if (bi == NB - 1 && t == 0) rs[N] = NE;
    __syncthreads();
    dcnt[t] = excl;
    __syncthreads();
    for (int j = bktbase + t; j < bktend; j += 1024) {
        int2 p = part[j];
        unsigned s = atomicAdd(&dcnt[p.x - lo], 1u);
        csr[bktbase + (int)s] = p.y;
    }
}

// ================= W transpose: WT[k*64+col], col<32 = Wl^T, col>=32 = Wr^T ==========
__global__ void wt_k(const float* __restrict__ wl_u, const float* __restrict__ wr_u,
                     const float* __restrict__ wl_i, const float* __restrict__ wr_i,
                     float* __restrict__ WTu, float* __restrict__ WTi) {
    int idx = blockIdx.x * 256 + threadIdx.x;   // 0..16383
    int half = idx >> 13;
    int r = idx & 8191;
    int k = r >> 6;
    int col = r & 63;
    const float* wl = half ? wl_i : wl_u;
    const float* wr = half ? wr_i : wr_u;
    float v = (col < 32) ? wl[col * FIN + k] : wr[(col - 32) * FIN + k];
    (half ? WTi : WTu)[k * 64 + col] = v;
}

// ================= proj128: X in LDS, W from global (L1/L2-hot WT) =================
__device__ __forceinline__ void proj128_body(const float* __restrict__ X,
                                             const float* __restrict__ WT,
                                             float* __restrict__ S, float* __restrict__ R,
                                             int N, int vb, float* sX) {
    int tid = threadIdx.x;
    int n0 = vb * 64;
#pragma unroll
    for (int it = 0; it < 8; ++it) {
        int idx = it * 256 + tid;
        int n = idx >> 5, k4 = (idx & 31) * 4;
        if (n0 + n < N) {
            float4 v = *(const float4*)(X + (size_t)(n0 + n) * FIN + k4);
            *(float4*)&sX[n * 132 + k4] = v;
        }
    }
    __syncthreads();
    int ct = tid & 15, nt = tid >> 4;
    int c0 = ct * 4;
    int nb = nt * 4;
    float acc[4][4];
#pragma unroll
    for (int j = 0; j < 4; ++j)
#pragma unroll
        for (int i = 0; i < 4; ++i) acc[j][i] = 0.f;
#pragma unroll 4
    for (int k = 0; k < FIN; ++k) {
        float4 w = *(const float4*)(WT + k * 64 + c0);
        float x0 = sX[(nb + 0) * 132 + k];
        float x1 = sX[(nb + 1) * 132 + k];
        float x2 = sX[(nb + 2) * 132 + k];
        float x3 = sX[(nb + 3) * 132 + k];
        acc[0][0] += x0 * w.x; acc[0][1] += x0 * w.y; acc[0][2] += x0 * w.z; acc[0][3] += x0 * w.w;
        acc[1][0] += x1 * w.x; acc[1][1] += x1 * w.y; acc[1][2] += x1 * w.z; acc[1][3] += x1 * w.w;
        acc[2][0] += x2 * w.x; acc[2][1] += x2 * w.y; acc[2][2] += x2 * w.z; acc[2][3] += x2 * w.w;
        acc[3][0] += x3 * w.x; acc[3][1] += x3 * w.y; acc[3][2] += x3 * w.z; acc[3][3] += x3 * w.w;
    }
#pragma unroll
    for (int j = 0; j < 4; ++j) {
        int node = n0 + nb + j;
        if (node < N) {
            float4 o;
            o.x = acc[j][0]; o.y = acc[j][1]; o.z = acc[j][2]; o.w = acc[j][3];
            if (c0 < 32) *(float4*)(S + (size_t)node * HH + c0) = o;
            else         *(float4*)(R + (size_t)node * HH + (c0 - 32)) = o;
        }
    }
}

__global__ __launch_bounds__(256) void p1_k(const float* __restrict__ xu,
                                            const float* __restrict__ xi,
                                            const float* __restrict__ WTu,
                                            const float* __restrict__ WTi,
                                            float* __restrict__ Su, float* __restrict__ Ru,
                                            float* __restrict__ Si, float* __restrict__ Ri) {
    __shared__ float sX[64 * 132];
    int b = blockIdx.x;
    if (b < G_P128U) proj128_body(xu, WTu, Su, Ru, NU, b, sX);
    else             proj128_body(xi, WTi, Si, Ri, NI, b - G_P128U, sX);
}

// ================= fused pull0 + proj32 =================
__global__ void p23_k(const int* __restrict__ csrI, const int* __restrict__ rsI,
                      const float* __restrict__ Su, float* __restrict__ Ri,
                      const float* __restrict__ b0_ui,
                      const float* __restrict__ wl1_iu, const float* __restrict__ wr1_ui,
                      float* __restrict__ Si2,
                      const int* __restrict__ csrU, const int* __restrict__ rsU,
                      const float* __restrict__ Si, float* __restrict__ Ru,
                      const float* __restrict__ b0_iu,
                      const float* __restrict__ wl1_ui, const float* __restrict__ wr1_iu,
                      float* __restrict__ Su2) {
    __shared__ float sWl[HH * 36];
    __shared__ float sWr[HH * 36];
    __shared__ float sH[8][36];
    int b = blockIdx.x;
    const int *csr, *rs;
    const float *S, *bias, *Wl, *Wr;
    float *Rb, *S2;
    int vb;
    if (b < G_P0I) {
        csr = csrI; rs = rsI; S = Su; Rb = Ri; bias = b0_ui;
        Wl = wl1_iu; Wr = wr1_ui; S2 = Si2; vb = b;
    } else {
        csr = csrU; rs = rsU; S = Si; Rb = Ru; bias = b0_iu;
        Wl = wl1_ui; Wr = wr1_iu; S2 = Su2; vb = b - G_P0I;
    }
    int tid = threadIdx.x;
    {
        float4 a = ((const float4*)Wl)[tid];
        float4 w = ((const float4*)Wr)[tid];
        int e0 = tid * 4;
        int o = e0 >> 5, k = e0 & 31;
        sWl[(k + 0) * 36 + o] = a.x;
        sWl[(k + 1) * 36 + o] = a.y;
        sWl[(k + 2) * 36 + o] = a.z;
        sWl[(k + 3) * 36 + o] = a.w;
        sWr[(k + 0) * 36 + o] = w.x;
        sWr[(k + 1) * 36 + o] = w.y;
        sWr[(k + 2) * 36 + o] = w.z;
        sWr[(k + 3) * 36 + o] = w.w;
    }
    int g = tid >> 5, c = tid & 31;
    int n = vb * 8 + g;
    int s0 = rs[n], s1 = rs[n + 1];
    float a0 = 0.f, a1 = 0.f, a2 = 0.f, a3 = 0.f;
    int j = s0;
    for (; j + 7 < s1; j += 8) {
        int i0 = csr[j], i1 = csr[j + 1], i2 = csr[j + 2], i3 = csr[j + 3];
        int i4 = csr[j + 4], i5 = csr[j + 5], i6 = csr[j + 6], i7 = csr[j + 7];
        float g0 = S[(size_t)i0 * HH + c];
        float g1 = S[(size_t)i1 * HH + c];
        float g2 = S[(size_t)i2 * HH + c];
        float g3 = S[(size_t)i3 * HH + c];
        float g4 = S[(size_t)i4 * HH + c];
        float g5 = S[(size_t)i5 * HH + c];
        float g6 = S[(size_t)i6 * HH + c];
        float g7 = S[(size_t)i7 * HH + c];
        a0 += g0; a1 += g1; a2 += g2; a3 += g3;
        a0 += g4; a1 += g5; a2 += g6; a3 += g7;
    }
    for (; j < s1; ++j) a0 += S[(size_t)csr[j] * HH + c];
    float acc = (a0 + a1) + (a2 + a3);
    float deg = (float)(s1 - s0);
    deg = deg > 1.f ? deg : 1.f;
    float v = acc / deg + Rb[(size_t)n * HH + c] + bias[c];
    float ss = v * v;
    ss += __shfl_xor(ss, 1);
    ss += __shfl_xor(ss, 2);
    ss += __shfl_xor(ss, 4);
    ss += __shfl_xor(ss, 8);
    ss += __shfl_xor(ss, 16);
    float nrm = sqrtf(ss);
    nrm = nrm > 1e-12f ? nrm : 1e-12f;
    v = v / nrm;
    v = v > 0.f ? v : 0.f;
    sH[g][c] = v;
    __syncthreads();
    float aL = 0.f, aR = 0.f;
#pragma unroll
    for (int k = 0; k < HH; ++k) {
        float x = sH[g][k];
        aL += x * sWl[k * 36 + c];
        aR += x * sWr[k * 36 + c];
    }
    S2[(size_t)n * HH + c] = aL;
    Rb[(size_t)n * HH + c] = aR;
}

// ================= pull1 + final =================
__device__ __forceinline__ void pull1f_body(const int* __restrict__ csr,
                                            const int* __restrict__ rs,
                                            const float* __restrict__ S,
                                            const float* __restrict__ R,
                                            const float* __restrict__ b1,
                                            const float* __restrict__ Wp,
                                            const float* __restrict__ bp,
                                            float* __restrict__ out, int vb, float* smem) {
    float* sWpT = smem;
    float* sH   = smem + HH * 36;
    int tid = threadIdx.x;
    {
        float4 a = ((const float4*)Wp)[tid];
        int e0 = tid * 4;
        int o = e0 >> 5, k = e0 & 31;
        sWpT[(k + 0) * 36 + o] = a.x;
        sWpT[(k + 1) * 36 + o] = a.y;
        sWpT[(k + 2) * 36 + o] = a.z;
        sWpT[(k + 3) * 36 + o] = a.w;
    }
    int g = tid >> 5;
    int n = vb * 8 + g;
    int c = tid & 31;
    int s0 = rs[n], s1 = rs[n + 1];
    float a0 = 0.f, a1 = 0.f, a2 = 0.f, a3 = 0.f;
    int j = s0;
    for (; j + 7 < s1; j += 8) {
        int i0 = csr[j], i1 = csr[j + 1], i2 = csr[j + 2], i3 = csr[j + 3];
        int i4 = csr[j + 4], i5 = csr[j + 5], i6 = csr[j + 6], i7 = csr[j + 7];
        float g0 = S[(size_t)i0 * HH + c];
        float g1 = S[(size_t)i1 * HH + c];
        float g2 = S[(size_t)i2 * HH + c];
        float g3 = S[(size_t)i3 * HH + c];
        float g4 = S[(size_t)i4 * HH + c];
        float g5 = S[(size_t)i5 * HH + c];
        float g6 = S[(size_t)i6 * HH + c];
        float g7 = S[(size_t)i7 * HH + c];
        a0 += g0; a1 += g1; a2 += g2; a3 += g3;
        a0 += g4; a1 += g5; a2 += g6; a3 += g7;
    }
    for (; j < s1; ++j) a0 += S[(size_t)csr[j] * HH + c];
    float acc = (a0 + a1) + (a2 + a3);
    float deg = (float)(s1 - s0);
    deg = deg > 1.f ? deg : 1.f;
    float v = acc / deg + R[(size_t)n * HH + c] + b1[c];
    float ss = v * v;
    ss += __shfl_xor(ss, 1);
    ss += __shfl_xor(ss, 2);
    ss += __shfl_xor(ss, 4);
    ss += __shfl_xor(ss, 8);
    ss += __shfl_xor(ss, 16);
    float nrm = sqrtf(ss);
    nrm = nrm > 1e-12f ? nrm : 1e-12f;
    v = v / nrm;
    v = v > 0.f ? v : 0.f;
    sH[g * 36 + c] = v;
    __syncthreads();
    float a2f = bp[c];
#pragma unroll
    for (int k = 0; k < HH; ++k) a2f += sH[g * 36 + k] * sWpT[k * 36 + c];
    float s2 = a2f * a2f;
    s2 += __shfl_xor(s2, 1);
    s2 += __shfl_xor(s2, 2);
    s2 += __shfl_xor(s2, 4);
    s2 += __shfl_xor(s2, 8);
    s2 += __shfl_xor(s2, 16);
    float nrm2 = sqrtf(s2);
    nrm2 = nrm2 > 1e-12f ? nrm2 : 1e-12f;
    out[(size_t)n * HH + c] = a2f / nrm2;
}

__global__ void p4_k(const int* __restrict__ csrU, const int* __restrict__ rsU,
                     const float* __restrict__ Si2, const float* __restrict__ Ru,
                     const float* __restrict__ b1_iu,
                     const float* __restrict__ wp_user, const float* __restrict__ bp_user,
                     const int* __restrict__ csrI, const int* __restrict__ rsI,
                     const float* __restrict__ Su2, const float* __restrict__ Ri,
                     const float* __restrict__ b1_ui,
                     const float* __restrict__ wp_item, const float* __restrict__ bp_item,
                     float* __restrict__ out) {
    __shared__ float smem[HH * 36 + 8 * 36];
    int b = blockIdx.x;
    if (b < G_P0U) {
        pull1f_body(csrU, rsU, Si2, Ru, b1_iu, wp_user, bp_user, out, b, smem);
    } else {
        pull1f_body(csrI, rsI, Su2, Ri, b1_ui, wp_item, bp_item,
                    out + (size_t)NU * HH, b - G_P0U, smem);
    }
}

// ================= host =================

extern "C" void kernel_launch(void* const* d_in, const int* in_sizes, int n_in,
                              void* d_out, int out_size, void* d_ws, size_t ws_size,
                              hipStream_t stream) {
    const float* x_user = (const float*)d_in[0];
    const float* x_item = (const float*)d_in[1];
    const int* eu = (const int*)d_in[2];
    const int* ei = (const int*)d_in[3];
    const float* wl0_ui = (const float*)d_in[4];
    const float* b0_ui  = (const float*)d_in[5];
    const float* wr0_ui = (const float*)d_in[6];
    const float* wl0_iu = (const float*)d_in[7];
    const float* b0_iu  = (const float*)d_in[8];
    const float* wr0_iu = (const float*)d_in[9];
    const float* wl1_ui = (const float*)d_in[10];
    const float* b1_ui  = (const float*)d_in[11];
    const float* wr1_ui = (const float*)d_in[12];
    const float* wl1_iu = (const float*)d_in[13];
    const float* b1_iu  = (const float*)d_in[14];
    const float* wr1_iu = (const float*)d_in[15];
    const float* wp_user = (const float*)d_in[16];
    const float* bp_user = (const float*)d_in[17];
    const float* wp_item = (const float*)d_in[18];
    const float* bp_item = (const float*)d_in[19];
    float* out = (float*)d_out;
    (void)in_sizes; (void)n_in; (void)out_size; (void)ws_size;

    char* base = (char*)d_ws;
    size_t off = 0;
    auto take = [&](size_t bytes) -> size_t {
        size_t o = off;
        off += (bytes + 255) & ~(size_t)255;
        return o;
    };
    size_t o_rsU  = take((size_t)(NU + 1) * 4);
    size_t o_rsI  = take((size_t)(NI + 1) * 4);
    size_t o_cntU = take((size_t)NBU * NCH * 4);
    size_t o_cntI = take((size_t)NBI * NCH * 4);
    size_t o_WTu  = take((size_t)FIN * 64 * 4);
    size_t o_WTi  = take((size_t)FIN * 64 * 4);
    size_t o_csrU = take((size_t)NE * 4);
    size_t o_csrI = take((size_t)NE * 4);
    size_t o_Su = take((size_t)NU * HH * 4);
    size_t o_Si = take((size_t)NI * HH * 4);
    size_t o_Ru = take((size_t)NU * HH * 4);   // also partI staging (8B*NE=6.55MB <= 12.8MB)
    size_t o_Ri = take((size_t)NI * HH * 4);
    size_t o_Su2 = take((size_t)NU * HH * 4);  // also partU staging
    size_t o_Si2 = take((size_t)NI * HH * 4);

    int* rsU  = (int*)(base + o_rsU);
    int* rsI  = (int*)(base + o_rsI);
    int* cntU = (int*)(base + o_cntU);
    int* cntI = (int*)(base + o_cntI);
    float* WTu = (float*)(base + o_WTu);
    float* WTi = (float*)(base + o_WTi);
    int* csrU = (int*)(base + o_csrU);
    int* csrI = (int*)(base + o_csrI);
    float* Su = (float*)(base + o_Su);
    float* Si = (float*)(base + o_Si);
    float* Ru = (float*)(base + o_Ru);
    float* Ri = (float*)(base + o_Ri);
    float* Su2 = (float*)(base + o_Su2);
    float* Si2 = (float*)(base + o_Si2);
    int2* partU = (int2*)(base + o_Su2);   // dead before Su2 written
    int2* partI = (int2*)(base + o_Ru);    // dead before Ru written

    // ---- W transposes (tiny) ----
    wt_k<<<64, 256, 0, stream>>>(wl0_ui, wr0_iu, wl0_iu, wr0_ui, WTu, WTi);

    // ---- radix CSR build (no global random atomics, no memset) ----
    cnt1_k<<<2 * NCH, 256, 0, stream>>>((const int4*)eu, (const int4*)ei, cntU, cntI);
    scan2_k<<<1, 1024, 0, stream>>>(cntU, NBU * NCH, cntI, NBI * NCH);
    part_k<<<2 * NCH, 256, 0, stream>>>((const int4*)eu, (const int4*)ei,
                                        cntU, cntI, partU, partI);
    build_k<<<NBU + NBI, 1024, 0, stream>>>(partU, partI, cntU, cntI,
                                            rsU, rsI, csrU, csrI);

    // ---- layer-0 projections (X-in-LDS, WT from cache) ----
    p1_k<<<G_P128U + G_P128I, 256, 0, stream>>>(x_user, x_item, WTu, WTi,
                                                Su, Ru, Si, Ri);

    // ---- layer-0 pulls fused with layer-1 projections ----
    p23_k<<<G_P0I + G_P0U, 256, 0, stream>>>(csrI, rsI, Su, Ri, b0_ui, wl1_iu, wr1_ui, Si2,
                                             csrU, rsU, Si, Ru, b0_iu, wl1_ui, wr1_iu, Su2);

    // ---- layer-1 pulls + final projections -> out ----
    p4_k<<<G_P0U + G_P0I, 256, 0, stream>>>(csrU, rsU, Si2, Ru, b1_iu, wp_user, bp_user,
                                            csrI, rsI, Su2, Ri, b1_ui, wp_item, bp_item,
                                            out);
}

// Round 14
// 265.345 us; speedup vs baseline: 1.0327x; 1.0327x over previous
//
#include <hip/hip_runtime.h>

#define NU 100000
#define NI 50000
#define NE 819200
#define FIN 128
#define HH 32

#define NCH 200         // edge chunks of 4096
#define NBU 98          // user buckets of 1024 nodes
#define NBI 49          // item buckets of 1024 nodes

#define G_P0I 6250      // NI/8
#define G_P0U 12500     // NU/8
#define G_P128U 1563    // ceil(NU/64)
#define G_P128I 782     // ceil(NI/64)

// ================= radix CSR build =================

__global__ void cnt1_k(const int4* __restrict__ eu4, const int4* __restrict__ ei4,
                       int* __restrict__ cntU, int* __restrict__ cntI) {
    __shared__ unsigned cnt[128];
    int b = blockIdx.x;
    int c, NB;
    const int4* D;
    int* M;
    if (b < NCH) { c = b; D = eu4; M = cntU; NB = NBU; }
    else         { c = b - NCH; D = ei4; M = cntI; NB = NBI; }
    int tid = threadIdx.x;
    if (tid < 128) cnt[tid] = 0u;
    __syncthreads();
    int base = c * 1024;
#pragma unroll
    for (int it = 0; it < 4; ++it) {
        int4 v = D[base + it * 256 + tid];
        atomicAdd(&cnt[v.x >> 10], 1u);
        atomicAdd(&cnt[v.y >> 10], 1u);
        atomicAdd(&cnt[v.z >> 10], 1u);
        atomicAdd(&cnt[v.w >> 10], 1u);
    }
    __syncthreads();
    for (int i = tid; i < NB; i += 256) M[i * NCH + c] = (int)cnt[i];
}

__global__ __launch_bounds__(1024) void scan2_k(int* __restrict__ aU, int nU,
                                                int* __restrict__ aI, int nI) {
    __shared__ int ts[1024];
    int t = threadIdx.x;
    for (int pass = 0; pass < 2; ++pass) {
        int* a = pass ? aI : aU;
        int n  = pass ? nI : nU;
        int nper = (n + 1023) / 1024;
        int beg = t * nper;
        int end = beg + nper; if (end > n) end = n;
        int s = 0;
        for (int i = beg; i < end; ++i) s += a[i];
        ts[t] = s;
        __syncthreads();
        int incl = s;
        for (int off = 1; off < 1024; off <<= 1) {
            int y = (t >= off) ? ts[t - off] : 0;
            __syncthreads();
            incl += y;
            ts[t] = incl;
            __syncthreads();
        }
        int run = incl - s;
        for (int i = beg; i < end; ++i) { int v = a[i]; a[i] = run; run += v; }
        __syncthreads();
    }
}

__global__ void part_k(const int4* __restrict__ eu4, const int4* __restrict__ ei4,
                       const int* __restrict__ cntU, const int* __restrict__ cntI,
                       int2* __restrict__ partU, int2* __restrict__ partI) {
    __shared__ unsigned cur[128];
    int b = blockIdx.x;
    int c, NB;
    const int4 *D, *P;
    const int* M;
    int2* out;
    if (b < NCH) { c = b; D = eu4; P = ei4; M = cntU; out = partU; NB = NBU; }
    else         { c = b - NCH; D = ei4; P = eu4; M = cntI; out = partI; NB = NBI; }
    int tid = threadIdx.x;
    for (int i = tid; i < NB; i += 256) cur[i] = (unsigned)M[i * NCH + c];
    __syncthreads();
    int base = c * 1024;
#pragma unroll
    for (int it = 0; it < 4; ++it) {
        int4 d = D[base + it * 256 + tid];
        int4 p = P[base + it * 256 + tid];
        unsigned s;
        s = atomicAdd(&cur[d.x >> 10], 1u); out[s] = make_int2(d.x, p.x);
        s = atomicAdd(&cur[d.y >> 10], 1u); out[s] = make_int2(d.y, p.y);
        s = atomicAdd(&cur[d.z >> 10], 1u); out[s] = make_int2(d.z, p.z);
        s = atomicAdd(&cur[d.w >> 10], 1u); out[s] = make_int2(d.w, p.w);
    }
}

__global__ __launch_bounds__(1024) void build_k(const int2* __restrict__ partU,
                                                const int2* __restrict__ partI,
                                                const int* __restrict__ cntU,
                                                const int* __restrict__ cntI,
                                                int* __restrict__ rsU, int* __restrict__ rsI,
                                                int* __restrict__ csrU, int* __restrict__ csrI) {
    __shared__ unsigned dcnt[1024];
    __shared__ unsigned sc[1024];
    int b = blockIdx.x;
    const int2* part;
    const int* M;
    int *rs, *csr;
    int bi, N, NB;
    if (b < NBU) { bi = b; part = partU; M = cntU; rs = rsU; csr = csrU; N = NU; NB = NBU; }
    else         { bi = b - NBU; part = partI; M = cntI; rs = rsI; csr = csrI; N = NI; NB = NBI; }
    int lo = bi * 1024;
    int bktbase = M[bi * NCH];
    int bktend = (bi + 1 < NB) ? M[(bi + 1) * NCH] : NE;
    int t = threadIdx.x;
    dcnt[t] = 0u;
    __syncthreads();
    for (int j = bktbase + t; j < bktend; j += 1024) {
        int2 p = part[j];
        atomicAdd(&dcnt[p.x - lo], 1u);
    }
    __syncthreads();
    unsigned cme = dcnt[t];
    sc[t] = cme;
    __syncthreads();
    unsigned incl = cme;
    for (int off = 1; off < 1024; off <<= 1) {
        unsigned y = (t >= off) ? sc[t - off] : 0u;
        __syncthreads();
        incl += y;
        sc[t] = incl;
        __syncthreads();
    }
    unsigned excl = incl - cme;
    if (lo + t < N) rs[lo + t] = bktbase + (int)excl;
    if (bi == NB - 1 && t == 0) rs[N] = NE;
    __syncthreads();
    dcnt[t] = excl;
    __syncthreads();
    for (int j = bktbase + t; j < bktend; j += 1024) {
        int2 p = part[j];
        unsigned s = atomicAdd(&dcnt[p.x - lo], 1u);
        csr[bktbase + (int)s] = p.y;
    }
}

// ================= proj128: W in LDS, X global->registers, no main-loop sync =========
__device__ __forceinline__ void proj128_body(const float* __restrict__ X,
                                             const float* __restrict__ Wl,
                                             const float* __restrict__ Wr,
                                             float* __restrict__ S, float* __restrict__ R,
                                             int N, int vb, float* sW) {
    int tid = threadIdx.x;
#pragma unroll
    for (int it = 0; it < 8; ++it) {           // 2048 float4 = 64 cols x 128 k
        int idx = it * 256 + tid;
        int col = idx & 63, k = (idx >> 6) * 4;
        const float* src = (col < 32) ? (Wl + col * FIN + k) : (Wr + (col - 32) * FIN + k);
        float4 w = *(const float4*)src;
        sW[(k + 0) * 68 + col] = w.x;
        sW[(k + 1) * 68 + col] = w.y;
        sW[(k + 2) * 68 + col] = w.z;
        sW[(k + 3) * 68 + col] = w.w;
    }
    __syncthreads();
    int ct = tid & 15, nt = tid >> 4;
    int c0 = ct * 4;
    int n0 = vb * 64 + nt * 4;
    int mA = n0 + 0; if (mA >= N) mA = N - 1;
    int mB = n0 + 1; if (mB >= N) mB = N - 1;
    int mC = n0 + 2; if (mC >= N) mC = N - 1;
    int mD = n0 + 3; if (mD >= N) mD = N - 1;
    const float* xA = X + (size_t)mA * FIN;
    const float* xB = X + (size_t)mB * FIN;
    const float* xC = X + (size_t)mC * FIN;
    const float* xD = X + (size_t)mD * FIN;
    float acc[4][4];
#pragma unroll
    for (int j = 0; j < 4; ++j)
#pragma unroll
        for (int i = 0; i < 4; ++i) acc[j][i] = 0.f;
#pragma unroll 4
    for (int k4 = 0; k4 < FIN; k4 += 4) {
        float4 a4 = *(const float4*)(xA + k4);
        float4 b4 = *(const float4*)(xB + k4);
        float4 c4 = *(const float4*)(xC + k4);
        float4 d4 = *(const float4*)(xD + k4);
        float xa[4] = {a4.x, a4.y, a4.z, a4.w};
        float xb[4] = {b4.x, b4.y, b4.z, b4.w};
        float xc[4] = {c4.x, c4.y, c4.z, c4.w};
        float xd[4] = {d4.x, d4.y, d4.z, d4.w};
#pragma unroll
        for (int kk = 0; kk < 4; ++kk) {
            float4 w = *(const float4*)&sW[(k4 + kk) * 68 + c0];
            acc[0][0] += xa[kk] * w.x; acc[0][1] += xa[kk] * w.y;
            acc[0][2] += xa[kk] * w.z; acc[0][3] += xa[kk] * w.w;
            acc[1][0] += xb[kk] * w.x; acc[1][1] += xb[kk] * w.y;
            acc[1][2] += xb[kk] * w.z; acc[1][3] += xb[kk] * w.w;
            acc[2][0] += xc[kk] * w.x; acc[2][1] += xc[kk] * w.y;
            acc[2][2] += xc[kk] * w.z; acc[2][3] += xc[kk] * w.w;
            acc[3][0] += xd[kk] * w.x; acc[3][1] += xd[kk] * w.y;
            acc[3][2] += xd[kk] * w.z; acc[3][3] += xd[kk] * w.w;
        }
    }
#pragma unroll
    for (int j = 0; j < 4; ++j) {
        int node = n0 + j;
        if (node < N) {
            float4 o;
            o.x = acc[j][0]; o.y = acc[j][1]; o.z = acc[j][2]; o.w = acc[j][3];
            if (c0 < 32) *(float4*)(S + (size_t)node * HH + c0) = o;
            else         *(float4*)(R + (size_t)node * HH + (c0 - 32)) = o;
        }
    }
}

__global__ __launch_bounds__(256) void p1_k(const float* __restrict__ xu,
                                            const float* __restrict__ xi,
                                            const float* __restrict__ wl0_ui,
                                            const float* __restrict__ wr0_iu,
                                            const float* __restrict__ wl0_iu,
                                            const float* __restrict__ wr0_ui,
                                            float* __restrict__ Su, float* __restrict__ Ru,
                                            float* __restrict__ Si, float* __restrict__ Ri) {
    __shared__ float sW[128 * 68];
    int b = blockIdx.x;
    if (b < G_P128U) proj128_body(xu, wl0_ui, wr0_iu, Su, Ru, NU, b, sW);
    else             proj128_body(xi, wl0_iu, wr0_ui, Si, Ri, NI, b - G_P128U, sW);
}

// ================= fused pull0 + proj32 =================
__global__ void p23_k(const int* __restrict__ csrI, const int* __restrict__ rsI,
                      const float* __restrict__ Su, float* __restrict__ Ri,
                      const float* __restrict__ b0_ui,
                      const float* __restrict__ wl1_iu, const float* __restrict__ wr1_ui,
                      float* __restrict__ Si2,
                      const int* __restrict__ csrU, const int* __restrict__ rsU,
                      const float* __restrict__ Si, float* __restrict__ Ru,
                      const float* __restrict__ b0_iu,
                      const float* __restrict__ wl1_ui, const float* __restrict__ wr1_iu,
                      float* __restrict__ Su2) {
    __shared__ float sWl[HH * 36];
    __shared__ float sWr[HH * 36];
    __shared__ float sH[8][36];
    int b = blockIdx.x;
    const int *csr, *rs;
    const float *S, *bias, *Wl, *Wr;
    float *Rb, *S2;
    int vb;
    if (b < G_P0I) {
        csr = csrI; rs = rsI; S = Su; Rb = Ri; bias = b0_ui;
        Wl = wl1_iu; Wr = wr1_ui; S2 = Si2; vb = b;
    } else {
        csr = csrU; rs = rsU; S = Si; Rb = Ru; bias = b0_iu;
        Wl = wl1_ui; Wr = wr1_iu; S2 = Su2; vb = b - G_P0I;
    }
    int tid = threadIdx.x;
    {
        float4 a = ((const float4*)Wl)[tid];
        float4 w = ((const float4*)Wr)[tid];
        int e0 = tid * 4;
        int o = e0 >> 5, k = e0 & 31;
        sWl[(k + 0) * 36 + o] = a.x;
        sWl[(k + 1) * 36 + o] = a.y;
        sWl[(k + 2) * 36 + o] = a.z;
        sWl[(k + 3) * 36 + o] = a.w;
        sWr[(k + 0) * 36 + o] = w.x;
        sWr[(k + 1) * 36 + o] = w.y;
        sWr[(k + 2) * 36 + o] = w.z;
        sWr[(k + 3) * 36 + o] = w.w;
    }
    int g = tid >> 5, c = tid & 31;
    int n = vb * 8 + g;
    int s0 = rs[n], s1 = rs[n + 1];
    float a0 = 0.f, a1 = 0.f, a2 = 0.f, a3 = 0.f;
    int j = s0;
    for (; j + 7 < s1; j += 8) {
        int i0 = csr[j], i1 = csr[j + 1], i2 = csr[j + 2], i3 = csr[j + 3];
        int i4 = csr[j + 4], i5 = csr[j + 5], i6 = csr[j + 6], i7 = csr[j + 7];
        float g0 = S[(size_t)i0 * HH + c];
        float g1 = S[(size_t)i1 * HH + c];
        float g2 = S[(size_t)i2 * HH + c];
        float g3 = S[(size_t)i3 * HH + c];
        float g4 = S[(size_t)i4 * HH + c];
        float g5 = S[(size_t)i5 * HH + c];
        float g6 = S[(size_t)i6 * HH + c];
        float g7 = S[(size_t)i7 * HH + c];
        a0 += g0; a1 += g1; a2 += g2; a3 += g3;
        a0 += g4; a1 += g5; a2 += g6; a3 += g7;
    }
    for (; j < s1; ++j) a0 += S[(size_t)csr[j] * HH + c];
    float acc = (a0 + a1) + (a2 + a3);
    float deg = (float)(s1 - s0);
    deg = deg > 1.f ? deg : 1.f;
    float v = acc / deg + Rb[(size_t)n * HH + c] + bias[c];
    float ss = v * v;
    ss += __shfl_xor(ss, 1);
    ss += __shfl_xor(ss, 2);
    ss += __shfl_xor(ss, 4);
    ss += __shfl_xor(ss, 8);
    ss += __shfl_xor(ss, 16);
    float nrm = sqrtf(ss);
    nrm = nrm > 1e-12f ? nrm : 1e-12f;
    v = v / nrm;
    v = v > 0.f ? v : 0.f;
    sH[g][c] = v;
    __syncthreads();
    float aL = 0.f, aR = 0.f;
#pragma unroll
    for (int k = 0; k < HH; ++k) {
        float x = sH[g][k];
        aL += x * sWl[k * 36 + c];
        aR += x * sWr[k * 36 + c];
    }
    S2[(size_t)n * HH + c] = aL;
    Rb[(size_t)n * HH + c] = aR;
}

// ================= pull1 + final =================
__device__ __forceinline__ void pull1f_body(const int* __restrict__ csr,
                                            const int* __restrict__ rs,
                                            const float* __restrict__ S,
                                            const float* __restrict__ R,
                                            const float* __restrict__ b1,
                                            const float* __restrict__ Wp,
                                            const float* __restrict__ bp,
                                            float* __restrict__ out, int vb, float* smem) {
    float* sWpT = smem;
    float* sH   = smem + HH * 36;
    int tid = threadIdx.x;
    {
        float4 a = ((const float4*)Wp)[tid];
        int e0 = tid * 4;
        int o = e0 >> 5, k = e0 & 31;
        sWpT[(k + 0) * 36 + o] = a.x;
        sWpT[(k + 1) * 36 + o] = a.y;
        sWpT[(k + 2) * 36 + o] = a.z;
        sWpT[(k + 3) * 36 + o] = a.w;
    }
    int g = tid >> 5;
    int n = vb * 8 + g;
    int c = tid & 31;
    int s0 = rs[n], s1 = rs[n + 1];
    float a0 = 0.f, a1 = 0.f, a2 = 0.f, a3 = 0.f;
    int j = s0;
    for (; j + 7 < s1; j += 8) {
        int i0 = csr[j], i1 = csr[j + 1], i2 = csr[j + 2], i3 = csr[j + 3];
        int i4 = csr[j + 4], i5 = csr[j + 5], i6 = csr[j + 6], i7 = csr[j + 7];
        float g0 = S[(size_t)i0 * HH + c];
        float g1 = S[(size_t)i1 * HH + c];
        float g2 = S[(size_t)i2 * HH + c];
        float g3 = S[(size_t)i3 * HH + c];
        float g4 = S[(size_t)i4 * HH + c];
        float g5 = S[(size_t)i5 * HH + c];
        float g6 = S[(size_t)i6 * HH + c];
        float g7 = S[(size_t)i7 * HH + c];
        a0 += g0; a1 += g1; a2 += g2; a3 += g3;
        a0 += g4; a1 += g5; a2 += g6; a3 += g7;
    }
    for (; j < s1; ++j) a0 += S[(size_t)csr[j] * HH + c];
    float acc = (a0 + a1) + (a2 + a3);
    float deg = (float)(s1 - s0);
    deg = deg > 1.f ? deg : 1.f;
    float v = acc / deg + R[(size_t)n * HH + c] + b1[c];
    float ss = v * v;
    ss += __shfl_xor(ss, 1);
    ss += __shfl_xor(ss, 2);
    ss += __shfl_xor(ss, 4);
    ss += __shfl_xor(ss, 8);
    ss += __shfl_xor(ss, 16);
    float nrm = sqrtf(ss);
    nrm = nrm > 1e-12f ? nrm : 1e-12f;
    v = v / nrm;
    v = v > 0.f ? v : 0.f;
    sH[g * 36 + c] = v;
    __syncthreads();
    float a2f = bp[c];
#pragma unroll
    for (int k = 0; k < HH; ++k) a2f += sH[g * 36 + k] * sWpT[k * 36 + c];
    float s2 = a2f * a2f;
    s2 += __shfl_xor(s2, 1);
    s2 += __shfl_xor(s2, 2);
    s2 += __shfl_xor(s2, 4);
    s2 += __shfl_xor(s2, 8);
    s2 += __shfl_xor(s2, 16);
    float nrm2 = sqrtf(s2);
    nrm2 = nrm2 > 1e-12f ? nrm2 : 1e-12f;
    out[(size_t)n * HH + c] = a2f / nrm2;
}

__global__ void p4_k(const int* __restrict__ csrU, const int* __restrict__ rsU,
                     const float* __restrict__ Si2, const float* __restrict__ Ru,
                     const float* __restrict__ b1_iu,
                     const float* __restrict__ wp_user, const float* __restrict__ bp_user,
                     const int* __restrict__ csrI, const int* __restrict__ rsI,
                     const float* __restrict__ Su2, const float* __restrict__ Ri,
                     const float* __restrict__ b1_ui,
                     const float* __restrict__ wp_item, const float* __restrict__ bp_item,
                     float* __restrict__ out) {
    __shared__ float smem[HH * 36 + 8 * 36];
    int b = blockIdx.x;
    if (b < G_P0U) {
        pull1f_body(csrU, rsU, Si2, Ru, b1_iu, wp_user, bp_user, out, b, smem);
    } else {
        pull1f_body(csrI, rsI, Su2, Ri, b1_ui, wp_item, bp_item,
                    out + (size_t)NU * HH, b - G_P0U, smem);
    }
}

// ================= host =================

extern "C" void kernel_launch(void* const* d_in, const int* in_sizes, int n_in,
                              void* d_out, int out_size, void* d_ws, size_t ws_size,
                              hipStream_t stream) {
    const float* x_user = (const float*)d_in[0];
    const float* x_item = (const float*)d_in[1];
    const int* eu = (const int*)d_in[2];
    const int* ei = (const int*)d_in[3];
    const float* wl0_ui = (const float*)d_in[4];
    const float* b0_ui  = (const float*)d_in[5];
    const float* wr0_ui = (const float*)d_in[6];
    const float* wl0_iu = (const float*)d_in[7];
    const float* b0_iu  = (const float*)d_in[8];
    const float* wr0_iu = (const float*)d_in[9];
    const float* wl1_ui = (const float*)d_in[10];
    const float* b1_ui  = (const float*)d_in[11];
    const float* wr1_ui = (const float*)d_in[12];
    const float* wl1_iu = (const float*)d_in[13];
    const float* b1_iu  = (const float*)d_in[14];
    const float* wr1_iu = (const float*)d_in[15];
    const float* wp_user = (const float*)d_in[16];
    const float* bp_user = (const float*)d_in[17];
    const float* wp_item = (const float*)d_in[18];
    const float* bp_item = (const float*)d_in[19];
    float* out = (float*)d_out;
    (void)in_sizes; (void)n_in; (void)out_size; (void)ws_size;

    char* base = (char*)d_ws;
    size_t off = 0;
    auto take = [&](size_t bytes) -> size_t {
        size_t o = off;
        off += (bytes + 255) & ~(size_t)255;
        return o;
    };
    size_t o_rsU  = take((size_t)(NU + 1) * 4);
    size_t o_rsI  = take((size_t)(NI + 1) * 4);
    size_t o_cntU = take((size_t)NBU * NCH * 4);
    size_t o_cntI = take((size_t)NBI * NCH * 4);
    size_t o_csrU = take((size_t)NE * 4);
    size_t o_csrI = take((size_t)NE * 4);
    size_t o_Su = take((size_t)NU * HH * 4);
    size_t o_Si = take((size_t)NI * HH * 4);
    size_t o_Ru = take((size_t)NU * HH * 4);   // also partI staging (8B*NE=6.55MB <= 12.8MB)
    size_t o_Ri = take((size_t)NI * HH * 4);
    size_t o_Su2 = take((size_t)NU * HH * 4);  // also partU staging
    size_t o_Si2 = take((size_t)NI * HH * 4);

    int* rsU  = (int*)(base + o_rsU);
    int* rsI  = (int*)(base + o_rsI);
    int* cntU = (int*)(base + o_cntU);
    int* cntI = (int*)(base + o_cntI);
    int* csrU = (int*)(base + o_csrU);
    int* csrI = (int*)(base + o_csrI);
    float* Su = (float*)(base + o_Su);
    float* Si = (float*)(base + o_Si);
    float* Ru = (float*)(base + o_Ru);
    float* Ri = (float*)(base + o_Ri);
    float* Su2 = (float*)(base + o_Su2);
    float* Si2 = (float*)(base + o_Si2);
    int2* partU = (int2*)(base + o_Su2);   // dead before Su2 written
    int2* partI = (int2*)(base + o_Ru);    // dead before Ru written

    // ---- radix CSR build (no global random atomics, no memset) ----
    cnt1_k<<<2 * NCH, 256, 0, stream>>>((const int4*)eu, (const int4*)ei, cntU, cntI);
    scan2_k<<<1, 1024, 0, stream>>>(cntU, NBU * NCH, cntI, NBI * NCH);
    part_k<<<2 * NCH, 256, 0, stream>>>((const int4*)eu, (const int4*)ei,
                                        cntU, cntI, partU, partI);
    build_k<<<NBU + NBI, 1024, 0, stream>>>(partU, partI, cntU, cntI,
                                            rsU, rsI, csrU, csrI);

    // ---- layer-0 projections (W-in-LDS, X->registers) ----
    p1_k<<<G_P128U + G_P128I, 256, 0, stream>>>(x_user, x_item, wl0_ui, wr0_iu,
                                                wl0_iu, wr0_ui, Su, Ru, Si, Ri);

    // ---- layer-0 pulls fused with layer-1 projections ----
    p23_k<<<G_P0I + G_P0U, 256, 0, stream>>>(csrI, rsI, Su, Ri, b0_ui, wl1_iu, wr1_ui, Si2,
                                             csrU, rsU, Si, Ru, b0_iu, wl1_ui, wr1_iu, Su2);

    // ---- layer-1 pulls + final projections -> out ----
    p4_k<<<G_P0U + G_P0I, 256, 0, stream>>>(csrU, rsU, Si2, Ru, b1_iu, wp_user, bp_user,
                                            csrI, rsI, Su2, Ri, b1_ui, wp_item, bp_item,
                                            out);
}

// Round 15
// 262.772 us; speedup vs baseline: 1.0428x; 1.0098x over previous
//
#include <hip/hip_runtime.h>

#define NU 100000
#define NI 50000
#define NE 819200
#define FIN 128
#define HH 32

#define NCH 200         // edge chunks of 4096
#define NBU 98          // user buckets of 1024 nodes
#define NBI 49          // item buckets of 1024 nodes

#define G_P0I 6250      // NI/8
#define G_P0U 12500     // NU/8
#define G_P1U 782       // ceil(NU/128)
#define G_P1I 391       // ceil(NI/128)

// ================= radix CSR build =================

__global__ void cnt1_k(const int4* __restrict__ eu4, const int4* __restrict__ ei4,
                       int* __restrict__ cntU, int* __restrict__ cntI) {
    __shared__ unsigned cnt[128];
    int b = blockIdx.x;
    int c, NB;
    const int4* D;
    int* M;
    if (b < NCH) { c = b; D = eu4; M = cntU; NB = NBU; }
    else         { c = b - NCH; D = ei4; M = cntI; NB = NBI; }
    int tid = threadIdx.x;
    if (tid < 128) cnt[tid] = 0u;
    __syncthreads();
    int base = c * 1024;
#pragma unroll
    for (int it = 0; it < 4; ++it) {
        int4 v = D[base + it * 256 + tid];
        atomicAdd(&cnt[v.x >> 10], 1u);
        atomicAdd(&cnt[v.y >> 10], 1u);
        atomicAdd(&cnt[v.z >> 10], 1u);
        atomicAdd(&cnt[v.w >> 10], 1u);
    }
    __syncthreads();
    for (int i = tid; i < NB; i += 256) M[i * NCH + c] = (int)cnt[i];
}

__global__ __launch_bounds__(1024) void scan2_k(int* __restrict__ aU, int nU,
                                                int* __restrict__ aI, int nI) {
    __shared__ int ts[1024];
    int t = threadIdx.x;
    for (int pass = 0; pass < 2; ++pass) {
        int* a = pass ? aI : aU;
        int n  = pass ? nI : nU;
        int nper = (n + 1023) / 1024;
        int beg = t * nper;
        int end = beg + nper; if (end > n) end = n;
        int s = 0;
        for (int i = beg; i < end; ++i) s += a[i];
        ts[t] = s;
        __syncthreads();
        int incl = s;
        for (int off = 1; off < 1024; off <<= 1) {
            int y = (t >= off) ? ts[t - off] : 0;
            __syncthreads();
            incl += y;
            ts[t] = incl;
            __syncthreads();
        }
        int run = incl - s;
        for (int i = beg; i < end; ++i) { int v = a[i]; a[i] = run; run += v; }
        __syncthreads();
    }
}

__global__ void part_k(const int4* __restrict__ eu4, const int4* __restrict__ ei4,
                       const int* __restrict__ cntU, const int* __restrict__ cntI,
                       int2* __restrict__ partU, int2* __restrict__ partI) {
    __shared__ unsigned cur[128];
    int b = blockIdx.x;
    int c, NB;
    const int4 *D, *P;
    const int* M;
    int2* out;
    if (b < NCH) { c = b; D = eu4; P = ei4; M = cntU; out = partU; NB = NBU; }
    else         { c = b - NCH; D = ei4; P = eu4; M = cntI; out = partI; NB = NBI; }
    int tid = threadIdx.x;
    for (int i = tid; i < NB; i += 256) cur[i] = (unsigned)M[i * NCH + c];
    __syncthreads();
    int base = c * 1024;
#pragma unroll
    for (int it = 0; it < 4; ++it) {
        int4 d = D[base + it * 256 + tid];
        int4 p = P[base + it * 256 + tid];
        unsigned s;
        s = atomicAdd(&cur[d.x >> 10], 1u); out[s] = make_int2(d.x, p.x);
        s = atomicAdd(&cur[d.y >> 10], 1u); out[s] = make_int2(d.y, p.y);
        s = atomicAdd(&cur[d.z >> 10], 1u); out[s] = make_int2(d.z, p.z);
        s = atomicAdd(&cur[d.w >> 10], 1u); out[s] = make_int2(d.w, p.w);
    }
}

__global__ __launch_bounds__(1024) void build_k(const int2* __restrict__ partU,
                                                const int2* __restrict__ partI,
                                                const int* __restrict__ cntU,
                                                const int* __restrict__ cntI,
                                                int* __restrict__ rsU, int* __restrict__ rsI,
                                                int* __restrict__ csrU, int* __restrict__ csrI) {
    __shared__ unsigned dcnt[1024];
    __shared__ unsigned sc[1024];
    int b = blockIdx.x;
    const int2* part;
    const int* M;
    int *rs, *csr;
    int bi, N, NB;
    if (b < NBU) { bi = b; part = partU; M = cntU; rs = rsU; csr = csrU; N = NU; NB = NBU; }
    else         { bi = b - NBU; part = partI; M = cntI; rs = rsI; csr = csrI; N = NI; NB = NBI; }
    int lo = bi * 1024;
    int bktbase = M[bi * NCH];
    int bktend = (bi + 1 < NB) ? M[(bi + 1) * NCH] : NE;
    int t = threadIdx.x;
    dcnt[t] = 0u;
    __syncthreads();
    for (int j = bktbase + t; j < bktend; j += 1024) {
        int2 p = part[j];
        atomicAdd(&dcnt[p.x - lo], 1u);
    }
    __syncthreads();
    unsigned cme = dcnt[t];
    sc[t] = cme;
    __syncthreads();
    unsigned incl = cme;
    for (int off = 1; off < 1024; off <<= 1) {
        unsigned y = (t >= off) ? sc[t - off] : 0u;
        __syncthreads();
        incl += y;
        sc[t] = incl;
        __syncthreads();
    }
    unsigned excl = incl - cme;
    if (lo + t < N) rs[lo + t] = bktbase + (int)excl;
    if (bi == NB - 1 && t == 0) rs[N] = NE;
    __syncthreads();
    dcnt[t] = excl;
    __syncthreads();
    for (int j = bktbase + t; j < bktend; j += 1024) {
        int2 p = part[j];
        unsigned s = atomicAdd(&dcnt[p.x - lo], 1u);
        csr[bktbase + (int)s] = p.y;
    }
}

// ======= proj128: W in LDS, X global->registers, 512 threads / 128 nodes per block =======
__device__ __forceinline__ void proj128_body(const float* __restrict__ X,
                                             const float* __restrict__ Wl,
                                             const float* __restrict__ Wr,
                                             float* __restrict__ S, float* __restrict__ R,
                                             int N, int vb, float* sW) {
    int tid = threadIdx.x;
#pragma unroll
    for (int it = 0; it < 4; ++it) {           // 2048 float4 = 64 cols x 128 k
        int idx = it * 512 + tid;
        int col = idx & 63, k = (idx >> 6) * 4;
        const float* src = (col < 32) ? (Wl + col * FIN + k) : (Wr + (col - 32) * FIN + k);
        float4 w = *(const float4*)src;
        sW[(k + 0) * 68 + col] = w.x;
        sW[(k + 1) * 68 + col] = w.y;
        sW[(k + 2) * 68 + col] = w.z;
        sW[(k + 3) * 68 + col] = w.w;
    }
    __syncthreads();
    int ct = tid & 15, nt = tid >> 4;          // nt in [0,32): 32 node-quads = 128 nodes
    int c0 = ct * 4;
    int n0 = vb * 128 + nt * 4;
    int mA = n0 + 0; if (mA >= N) mA = N - 1;
    int mB = n0 + 1; if (mB >= N) mB = N - 1;
    int mC = n0 + 2; if (mC >= N) mC = N - 1;
    int mD = n0 + 3; if (mD >= N) mD = N - 1;
    const float* xA = X + (size_t)mA * FIN;
    const float* xB = X + (size_t)mB * FIN;
    const float* xC = X + (size_t)mC * FIN;
    const float* xD = X + (size_t)mD * FIN;
    float acc[4][4];
#pragma unroll
    for (int j = 0; j < 4; ++j)
#pragma unroll
        for (int i = 0; i < 4; ++i) acc[j][i] = 0.f;
#pragma unroll 4
    for (int k4 = 0; k4 < FIN; k4 += 4) {
        float4 a4 = *(const float4*)(xA + k4);
        float4 b4 = *(const float4*)(xB + k4);
        float4 c4 = *(const float4*)(xC + k4);
        float4 d4 = *(const float4*)(xD + k4);
        float xa[4] = {a4.x, a4.y, a4.z, a4.w};
        float xb[4] = {b4.x, b4.y, b4.z, b4.w};
        float xc[4] = {c4.x, c4.y, c4.z, c4.w};
        float xd[4] = {d4.x, d4.y, d4.z, d4.w};
#pragma unroll
        for (int kk = 0; kk < 4; ++kk) {
            float4 w = *(const float4*)&sW[(k4 + kk) * 68 + c0];
            acc[0][0] += xa[kk] * w.x; acc[0][1] += xa[kk] * w.y;
            acc[0][2] += xa[kk] * w.z; acc[0][3] += xa[kk] * w.w;
            acc[1][0] += xb[kk] * w.x; acc[1][1] += xb[kk] * w.y;
            acc[1][2] += xb[kk] * w.z; acc[1][3] += xb[kk] * w.w;
            acc[2][0] += xc[kk] * w.x; acc[2][1] += xc[kk] * w.y;
            acc[2][2] += xc[kk] * w.z; acc[2][3] += xc[kk] * w.w;
            acc[3][0] += xd[kk] * w.x; acc[3][1] += xd[kk] * w.y;
            acc[3][2] += xd[kk] * w.z; acc[3][3] += xd[kk] * w.w;
        }
    }
#pragma unroll
    for (int j = 0; j < 4; ++j) {
        int node = n0 + j;
        if (node < N) {
            float4 o;
            o.x = acc[j][0]; o.y = acc[j][1]; o.z = acc[j][2]; o.w = acc[j][3];
            if (c0 < 32) *(float4*)(S + (size_t)node * HH + c0) = o;
            else         *(float4*)(R + (size_t)node * HH + (c0 - 32)) = o;
        }
    }
}

__global__ __launch_bounds__(512) void p1_k(const float* __restrict__ xu,
                                            const float* __restrict__ xi,
                                            const float* __restrict__ wl0_ui,
                                            const float* __restrict__ wr0_iu,
                                            const float* __restrict__ wl0_iu,
                                            const float* __restrict__ wr0_ui,
                                            float* __restrict__ Su, float* __restrict__ Ru,
                                            float* __restrict__ Si, float* __restrict__ Ri) {
    __shared__ float sW[128 * 68];
    int b = blockIdx.x;
    if (b < G_P1U) proj128_body(xu, wl0_ui, wr0_iu, Su, Ru, NU, b, sW);
    else           proj128_body(xi, wl0_iu, wr0_ui, Si, Ri, NI, b - G_P1U, sW);
}

// ================= fused pull0 + proj32 =================
__global__ void p23_k(const int* __restrict__ csrI, const int* __restrict__ rsI,
                      const float* __restrict__ Su, float* __restrict__ Ri,
                      const float* __restrict__ b0_ui,
                      const float* __restrict__ wl1_iu, const float* __restrict__ wr1_ui,
                      float* __restrict__ Si2,
                      const int* __restrict__ csrU, const int* __restrict__ rsU,
                      const float* __restrict__ Si, float* __restrict__ Ru,
                      const float* __restrict__ b0_iu,
                      const float* __restrict__ wl1_ui, const float* __restrict__ wr1_iu,
                      float* __restrict__ Su2) {
    __shared__ float sWl[HH * 36];
    __shared__ float sWr[HH * 36];
    __shared__ float sH[8][36];
    int b = blockIdx.x;
    const int *csr, *rs;
    const float *S, *bias, *Wl, *Wr;
    float *Rb, *S2;
    int vb;
    if (b < G_P0I) {
        csr = csrI; rs = rsI; S = Su; Rb = Ri; bias = b0_ui;
        Wl = wl1_iu; Wr = wr1_ui; S2 = Si2; vb = b;
    } else {
        csr = csrU; rs = rsU; S = Si; Rb = Ru; bias = b0_iu;
        Wl = wl1_ui; Wr = wr1_iu; S2 = Su2; vb = b - G_P0I;
    }
    int tid = threadIdx.x;
    {
        float4 a = ((const float4*)Wl)[tid];
        float4 w = ((const float4*)Wr)[tid];
        int e0 = tid * 4;
        int o = e0 >> 5, k = e0 & 31;
        sWl[(k + 0) * 36 + o] = a.x;
        sWl[(k + 1) * 36 + o] = a.y;
        sWl[(k + 2) * 36 + o] = a.z;
        sWl[(k + 3) * 36 + o] = a.w;
        sWr[(k + 0) * 36 + o] = w.x;
        sWr[(k + 1) * 36 + o] = w.y;
        sWr[(k + 2) * 36 + o] = w.z;
        sWr[(k + 3) * 36 + o] = w.w;
    }
    int g = tid >> 5, c = tid & 31;
    int n = vb * 8 + g;
    int s0 = rs[n], s1 = rs[n + 1];
    float a0 = 0.f, a1 = 0.f, a2 = 0.f, a3 = 0.f;
    int j = s0;
    for (; j + 7 < s1; j += 8) {
        int i0 = csr[j], i1 = csr[j + 1], i2 = csr[j + 2], i3 = csr[j + 3];
        int i4 = csr[j + 4], i5 = csr[j + 5], i6 = csr[j + 6], i7 = csr[j + 7];
        float g0 = S[(size_t)i0 * HH + c];
        float g1 = S[(size_t)i1 * HH + c];
        float g2 = S[(size_t)i2 * HH + c];
        float g3 = S[(size_t)i3 * HH + c];
        float g4 = S[(size_t)i4 * HH + c];
        float g5 = S[(size_t)i5 * HH + c];
        float g6 = S[(size_t)i6 * HH + c];
        float g7 = S[(size_t)i7 * HH + c];
        a0 += g0; a1 += g1; a2 += g2; a3 += g3;
        a0 += g4; a1 += g5; a2 += g6; a3 += g7;
    }
    for (; j < s1; ++j) a0 += S[(size_t)csr[j] * HH + c];
    float acc = (a0 + a1) + (a2 + a3);
    float deg = (float)(s1 - s0);
    deg = deg > 1.f ? deg : 1.f;
    float v = acc / deg + Rb[(size_t)n * HH + c] + bias[c];
    float ss = v * v;
    ss += __shfl_xor(ss, 1);
    ss += __shfl_xor(ss, 2);
    ss += __shfl_xor(ss, 4);
    ss += __shfl_xor(ss, 8);
    ss += __shfl_xor(ss, 16);
    float nrm = sqrtf(ss);
    nrm = nrm > 1e-12f ? nrm : 1e-12f;
    v = v / nrm;
    v = v > 0.f ? v : 0.f;
    sH[g][c] = v;
    __syncthreads();
    float aL = 0.f, aR = 0.f;
#pragma unroll
    for (int k = 0; k < HH; ++k) {
        float x = sH[g][k];
        aL += x * sWl[k * 36 + c];
        aR += x * sWr[k * 36 + c];
    }
    S2[(size_t)n * HH + c] = aL;
    Rb[(size_t)n * HH + c] = aR;
}

// ================= pull1 + final =================
__device__ __forceinline__ void pull1f_body(const int* __restrict__ csr,
                                            const int* __restrict__ rs,
                                            const float* __restrict__ S,
                                            const float* __restrict__ R,
                                            const float* __restrict__ b1,
                                            const float* __restrict__ Wp,
                                            const float* __restrict__ bp,
                                            float* __restrict__ out, int vb, float* smem) {
    float* sWpT = smem;
    float* sH   = smem + HH * 36;
    int tid = threadIdx.x;
    {
        float4 a = ((const float4*)Wp)[tid];
        int e0 = tid * 4;
        int o = e0 >> 5, k = e0 & 31;
        sWpT[(k + 0) * 36 + o] = a.x;
        sWpT[(k + 1) * 36 + o] = a.y;
        sWpT[(k + 2) * 36 + o] = a.z;
        sWpT[(k + 3) * 36 + o] = a.w;
    }
    int g = tid >> 5;
    int n = vb * 8 + g;
    int c = tid & 31;
    int s0 = rs[n], s1 = rs[n + 1];
    float a0 = 0.f, a1 = 0.f, a2 = 0.f, a3 = 0.f;
    int j = s0;
    for (; j + 7 < s1; j += 8) {
        int i0 = csr[j], i1 = csr[j + 1], i2 = csr[j + 2], i3 = csr[j + 3];
        int i4 = csr[j + 4], i5 = csr[j + 5], i6 = csr[j + 6], i7 = csr[j + 7];
        float g0 = S[(size_t)i0 * HH + c];
        float g1 = S[(size_t)i1 * HH + c];
        float g2 = S[(size_t)i2 * HH + c];
        float g3 = S[(size_t)i3 * HH + c];
        float g4 = S[(size_t)i4 * HH + c];
        float g5 = S[(size_t)i5 * HH + c];
        float g6 = S[(size_t)i6 * HH + c];
        float g7 = S[(size_t)i7 * HH + c];
        a0 += g0; a1 += g1; a2 += g2; a3 += g3;
        a0 += g4; a1 += g5; a2 += g6; a3 += g7;
    }
    for (; j < s1; ++j) a0 += S[(size_t)csr[j] * HH + c];
    float acc = (a0 + a1) + (a2 + a3);
    float deg = (float)(s1 - s0);
    deg = deg > 1.f ? deg : 1.f;
    float v = acc / deg + R[(size_t)n * HH + c] + b1[c];
    float ss = v * v;
    ss += __shfl_xor(ss, 1);
    ss += __shfl_xor(ss, 2);
    ss += __shfl_xor(ss, 4);
    ss += __shfl_xor(ss, 8);
    ss += __shfl_xor(ss, 16);
    float nrm = sqrtf(ss);
    nrm = nrm > 1e-12f ? nrm : 1e-12f;
    v = v / nrm;
    v = v > 0.f ? v : 0.f;
    sH[g * 36 + c] = v;
    __syncthreads();
    float a2f = bp[c];
#pragma unroll
    for (int k = 0; k < HH; ++k) a2f += sH[g * 36 + k] * sWpT[k * 36 + c];
    float s2 = a2f * a2f;
    s2 += __shfl_xor(s2, 1);
    s2 += __shfl_xor(s2, 2);
    s2 += __shfl_xor(s2, 4);
    s2 += __shfl_xor(s2, 8);
    s2 += __shfl_xor(s2, 16);
    float nrm2 = sqrtf(s2);
    nrm2 = nrm2 > 1e-12f ? nrm2 : 1e-12f;
    out[(size_t)n * HH + c] = a2f / nrm2;
}

__global__ void p4_k(const int* __restrict__ csrU, const int* __restrict__ rsU,
                     const float* __restrict__ Si2, const float* __restrict__ Ru,
                     const float* __restrict__ b1_iu,
                     const float* __restrict__ wp_user, const float* __restrict__ bp_user,
                     const int* __restrict__ csrI, const int* __restrict__ rsI,
                     const float* __restrict__ Su2, const float* __restrict__ Ri,
                     const float* __restrict__ b1_ui,
                     const float* __restrict__ wp_item, const float* __restrict__ bp_item,
                     float* __restrict__ out) {
    __shared__ float smem[HH * 36 + 8 * 36];
    int b = blockIdx.x;
    if (b < G_P0U) {
        pull1f_body(csrU, rsU, Si2, Ru, b1_iu, wp_user, bp_user, out, b, smem);
    } else {
        pull1f_body(csrI, rsI, Su2, Ri, b1_ui, wp_item, bp_item,
                    out + (size_t)NU * HH, b - G_P0U, smem);
    }
}

// ================= host =================

extern "C" void kernel_launch(void* const* d_in, const int* in_sizes, int n_in,
                              void* d_out, int out_size, void* d_ws, size_t ws_size,
                              hipStream_t stream) {
    const float* x_user = (const float*)d_in[0];
    const float* x_item = (const float*)d_in[1];
    const int* eu = (const int*)d_in[2];
    const int* ei = (const int*)d_in[3];
    const float* wl0_ui = (const float*)d_in[4];
    const float* b0_ui  = (const float*)d_in[5];
    const float* wr0_ui = (const float*)d_in[6];
    const float* wl0_iu = (const float*)d_in[7];
    const float* b0_iu  = (const float*)d_in[8];
    const float* wr0_iu = (const float*)d_in[9];
    const float* wl1_ui = (const float*)d_in[10];
    const float* b1_ui  = (const float*)d_in[11];
    const float* wr1_ui = (const float*)d_in[12];
    const float* wl1_iu = (const float*)d_in[13];
    const float* b1_iu  = (const float*)d_in[14];
    const float* wr1_iu = (const float*)d_in[15];
    const float* wp_user = (const float*)d_in[16];
    const float* bp_user = (const float*)d_in[17];
    const float* wp_item = (const float*)d_in[18];
    const float* bp_item = (const float*)d_in[19];
    float* out = (float*)d_out;
    (void)in_sizes; (void)n_in; (void)out_size; (void)ws_size;

    char* base = (char*)d_ws;
    size_t off = 0;
    auto take = [&](size_t bytes) -> size_t {
        size_t o = off;
        off += (bytes + 255) & ~(size_t)255;
        return o;
    };
    size_t o_rsU  = take((size_t)(NU + 1) * 4);
    size_t o_rsI  = take((size_t)(NI + 1) * 4);
    size_t o_cntU = take((size_t)NBU * NCH * 4);
    size_t o_cntI = take((size_t)NBI * NCH * 4);
    size_t o_csrU = take((size_t)NE * 4);
    size_t o_csrI = take((size_t)NE * 4);
    size_t o_Su = take((size_t)NU * HH * 4);
    size_t o_Si = take((size_t)NI * HH * 4);
    size_t o_Ru = take((size_t)NU * HH * 4);   // also partI staging (8B*NE=6.55MB <= 12.8MB)
    size_t o_Ri = take((size_t)NI * HH * 4);
    size_t o_Su2 = take((size_t)NU * HH * 4);  // also partU staging
    size_t o_Si2 = take((size_t)NI * HH * 4);

    int* rsU  = (int*)(base + o_rsU);
    int* rsI  = (int*)(base + o_rsI);
    int* cntU = (int*)(base + o_cntU);
    int* cntI = (int*)(base + o_cntI);
    int* csrU = (int*)(base + o_csrU);
    int* csrI = (int*)(base + o_csrI);
    float* Su = (float*)(base + o_Su);
    float* Si = (float*)(base + o_Si);
    float* Ru = (float*)(base + o_Ru);
    float* Ri = (float*)(base + o_Ri);
    float* Su2 = (float*)(base + o_Su2);
    float* Si2 = (float*)(base + o_Si2);
    int2* partU = (int2*)(base + o_Su2);   // dead before Su2 written
    int2* partI = (int2*)(base + o_Ru);    // dead before Ru written

    // ---- radix CSR build (no global random atomics, no memset) ----
    cnt1_k<<<2 * NCH, 256, 0, stream>>>((const int4*)eu, (const int4*)ei, cntU, cntI);
    scan2_k<<<1, 1024, 0, stream>>>(cntU, NBU * NCH, cntI, NBI * NCH);
    part_k<<<2 * NCH, 256, 0, stream>>>((const int4*)eu, (const int4*)ei,
                                        cntU, cntI, partU, partI);
    build_k<<<NBU + NBI, 1024, 0, stream>>>(partU, partI, cntU, cntI,
                                            rsU, rsI, csrU, csrI);

    // ---- layer-0 projections (W-in-LDS, X->registers, 512 threads) ----
    p1_k<<<G_P1U + G_P1I, 512, 0, stream>>>(x_user, x_item, wl0_ui, wr0_iu,
                                            wl0_iu, wr0_ui, Su, Ru, Si, Ri);

    // ---- layer-0 pulls fused with layer-1 projections ----
    p23_k<<<G_P0I + G_P0U, 256, 0, stream>>>(csrI, rsI, Su, Ri, b0_ui, wl1_iu, wr1_ui, Si2,
                                             csrU, rsU, Si, Ru, b0_iu, wl1_ui, wr1_iu, Su2);

    // ---- layer-1 pulls + final projections -> out ----
    p4_k<<<G_P0U + G_P0I, 256, 0, stream>>>(csrU, rsU, Si2, Ru, b1_iu, wp_user, bp_user,
                                            csrI, rsI, Su2, Ri, b1_ui, wp_item, bp_item,
                                            out);
}